// Round 5
// baseline (277.250 us; speedup 1.0000x reference)
//
#include <hip/hip_runtime.h>

typedef unsigned short ushort_t;
typedef unsigned int uint_t;

using bf16x8 = __attribute__((ext_vector_type(8))) short;
using f32x4  = __attribute__((ext_vector_type(4))) float;

// ---------- helpers ----------
__device__ __forceinline__ ushort_t f2b(float f){
    union { float f; uint_t u; } v; v.f = f;
    uint_t u = v.u;
    uint_t r = (u + 0x7FFFu + ((u >> 16) & 1u)) >> 16;   // RNE
    return (ushort_t)r;
}

// ---------- weight prep: f32 -> bf16 (+ conv restride) ----------
__global__ void prep_k(const float* __restrict__ vW, const float* __restrict__ Wx,
                       const float* __restrict__ Wh, const float* __restrict__ cW,
                       const float* __restrict__ sW, const float* __restrict__ oW,
                       const float* __restrict__ pW, ushort_t* __restrict__ wb)
{
    int idx = blockIdx.x * 256 + threadIdx.x;
    switch (blockIdx.y){
    case 0: if (idx < 16384) wb[idx]          = f2b(vW[idx]);           break;
    case 1: if (idx < 65536) wb[16384  + idx] = f2b(Wx[idx]);           break; // Wx0
    case 2: if (idx < 65536) wb[81920  + idx] = f2b(Wh[idx]);           break; // Wh0
    case 3: if (idx < 65536) wb[147456 + idx] = f2b(Wx[65536 + idx]);   break; // Wx1
    case 4: if (idx < 65536) wb[212992 + idx] = f2b(Wh[65536 + idx]);   break; // Wh1
    case 5: if (idx < 49152){                                                  // conv [k][o][i]
                int k = idx >> 14; int oi = idx & 16383;
                wb[278528 + idx] = f2b(cW[oi * 3 + k]);
            } break;
    case 6: if (idx < 16384) wb[327680 + idx] = f2b(sW[idx]);           break;
    case 7: if (idx < 16384) wb[344064 + idx] = f2b(oW[idx]);           break;
    case 8: if (idx < 12288) wb[360448 + idx] = f2b(pW[idx]);           break;
    }
}

// ---------- patch embed + layernorm ----------
__global__ void embed_ln_k(const float* __restrict__ x, const float* __restrict__ eW,
                           const float* __restrict__ eb, const float* __restrict__ lng,
                           const float* __restrict__ lnb,
                           float* __restrict__ xnF, ushort_t* __restrict__ xnB)
{
    const int e  = threadIdx.x;
    const int bc = blockIdx.x;
    const int b  = bc / 21, c = bc % 21;
    const int wid = threadIdx.x >> 6;

    float w[16];
#pragma unroll
    for (int p = 0; p < 16; ++p) w[p] = eW[e * 16 + p];
    const float bias = eb[e], gam = lng[e], bet = lnb[e];

    __shared__ float patch[16];
    __shared__ float red[4];

    for (int n = 0; n < 8; ++n){
        if (e < 16) patch[e] = x[(b * 128 + n * 16 + e) * 21 + c];
        __syncthreads();
        float v = bias;
#pragma unroll
        for (int p = 0; p < 16; ++p) v += w[p] * patch[p];

        float s = v, sq = v * v;
#pragma unroll
        for (int m = 32; m >= 1; m >>= 1){
            s  += __shfl_xor(s,  m);
            sq += __shfl_xor(sq, m);
        }
        if ((threadIdx.x & 63) == 0){ red[wid] = s; red[2 + wid] = sq; }
        __syncthreads();
        float S  = red[0] + red[1];
        float SQ = red[2] + red[3];
        float mean = S * (1.f / 128.f);
        float var  = SQ * (1.f / 128.f) - mean * mean;
        float r    = rsqrtf(var + 1e-5f);
        float y    = (v - mean) * r * gam + bet;
        int row = bc * 8 + n;
        xnF[row * 128 + e] = y;
        xnB[row * 128 + e] = f2b(y);
        __syncthreads();
    }
}

// ---------- generic MFMA matmul: Y(5376 x OUT) = A(5376x128) @ W(OUTx128)^T + bias ----------
__global__ void mm16_k(const ushort_t* __restrict__ A, const ushort_t* __restrict__ W,
                       const float* __restrict__ bias, const float* __restrict__ resid,
                       float* __restrict__ outF, ushort_t* __restrict__ outB, int OUT)
{
    const int lane = threadIdx.x & 63, wave = threadIdx.x >> 6;
    const int rowbase = blockIdx.x * 64 + wave * 16;
    const int r0 = lane & 15, g = lane >> 4;

    bf16x8 a[4];
    const ushort_t* ap = A + (rowbase + r0) * 128 + g * 8;
#pragma unroll
    for (int kt = 0; kt < 4; ++kt) a[kt] = *(const bf16x8*)(ap + kt * 32);

    const int ntiles = OUT >> 4;
    for (int nt = 0; nt < ntiles; ++nt){
        const int col = nt * 16 + r0;
        float bv = bias[col];
        f32x4 acc = {bv, bv, bv, bv};
        const ushort_t* wp = W + col * 128 + g * 8;
#pragma unroll
        for (int kt = 0; kt < 4; ++kt)
            acc = __builtin_amdgcn_mfma_f32_16x16x32_bf16(a[kt], *(const bf16x8*)(wp + kt * 32), acc, 0, 0, 0);
#pragma unroll
        for (int q = 0; q < 4; ++q){
            int row = rowbase + g * 4 + q;
            float val = acc[q];
            if (resid) val += resid[row * 128 + col];
            if (outF)  outF[row * OUT + col] = val;
            if (outB)  outB[row * OUT + col] = f2b(val);
        }
    }
}

// ---------- persistent 2-layer LSTM, layer-pipelined, all weights in registers ----------
// grid 42, block 512 (8 waves). 16 batch rows per block.
// Phase ph (0..64): L0(t=ph) [ph<64] and L1(t=ph-1) [ph>0], sharing the h0(ph-1)
// fragment. Wh0+Wx1+Wh1 all register-resident (192 regs; overflow -> AGPR, MFMA
// reads AGPR operands natively on gfx950). Single acc array (X0 prefetch lands in
// it after EW-B). All LDS addresses hoisted; parity via ds-offset immediates.
__global__ __launch_bounds__(512, 2) void lstm_k(
    const float* __restrict__ X0, const ushort_t* __restrict__ Wh0,
    const ushort_t* __restrict__ Wx1, const ushort_t* __restrict__ Wh1,
    const float* __restrict__ lb, ushort_t* __restrict__ outB)
{
    __shared__ ushort_t hbuf[4][2048];   // [h0 p0][h0 p1][h1 p0][h1 p1]

    const int tid = threadIdx.x;
    const int wid = tid >> 6, lane = tid & 63;
    const int r0 = lane & 15, g = lane >> 4;
    const int sw = r0 & 7;
    const int bcb = blockIdx.x * 16;
    const float K1 = 1.44269504f, K2 = 2.88539008f;

    for (int i = tid; i < 8192; i += 512) ((ushort_t*)hbuf)[i] = 0;

    // register-resident weights (B-fragments, col = cb + r0, k-slice kt)
    bf16x8 wh0[4][4], wh1[4][4], wx1r[4][4];
#pragma unroll
    for (int t4 = 0; t4 < 4; ++t4){
        const int cb = t4 * 128 + wid * 16;
#pragma unroll
        for (int kt = 0; kt < 4; ++kt){
            wh0[t4][kt]  = *(const bf16x8*)(Wh0 + (cb + r0) * 128 + kt * 32 + g * 8);
            wh1[t4][kt]  = *(const bf16x8*)(Wh1 + (cb + r0) * 128 + kt * 32 + g * 8);
            wx1r[t4][kt] = *(const bf16x8*)(Wx1 + (cb + r0) * 128 + kt * 32 + g * 8);
        }
    }
    float b1v[4];
#pragma unroll
    for (int t4 = 0; t4 < 4; ++t4) b1v[t4] = lb[512 + t4 * 128 + wid * 16 + r0];

    // hoisted LDS read addresses (per kt, swizzle baked in); h1 = +8192B, parity = +-4096B imm
    const char* adr[4];
#pragma unroll
    for (int kt = 0; kt < 4; ++kt)
        adr[kt] = (const char*)hbuf + r0 * 256 + (((kt * 32 + g * 8) ^ (sw << 3)) << 1);
    // hoisted LDS write addresses (per q); h1 = +8192B, parity = +pp*4096B imm
    char* wrq[4];
#pragma unroll
    for (int q = 0; q < 4; ++q){
        int row = g * 4 + q;
        wrq[q] = (char*)hbuf + row * 256 + (((wid * 16 + r0) ^ ((row & 7) << 3)) << 1);
    }
    // X0 running pointers (per q), starting at tn=1; t4 via +512B immediates
    const char* xp[4];
#pragma unroll
    for (int q = 0; q < 4; ++q)
        xp[q] = (const char*)(X0 + (bcb + g * 4 + q) * 4096 + wid * 16 + r0) + 2048;
    int tnn = 1;

    float c0[4] = {0,0,0,0}, c1[4] = {0,0,0,0};

    // acc preloaded with X0(t=0) slice (= Wx0@ctx + b0)
    f32x4 acc[4];
#pragma unroll
    for (int t4 = 0; t4 < 4; ++t4)
#pragma unroll
        for (int q = 0; q < 4; ++q)
            acc[t4][q] = *(const float*)(xp[q] - 2048 + t4 * 512);

    __syncthreads();

#pragma unroll 1
    for (int tt = 0; tt < 32; ++tt){
#pragma unroll
        for (int pp = 0; pp < 2; ++pp){
            const int ph = tt * 2 + pp;
            const int RDO = (pp ^ 1) * 4096;     // buffers written in phase ph-1
            const int WRO = pp * 4096;

            bf16x8 a0[4], ah[4];
#pragma unroll
            for (int kt = 0; kt < 4; ++kt){
                a0[kt] = *(const bf16x8*)(adr[kt] + RDO);          // h0(ph-1)
                ah[kt] = *(const bf16x8*)(adr[kt] + 8192 + RDO);   // h1(ph-2)
            }

            // ---- L0 MFMAs (t = ph): acc = X0(ph) + Wh0 @ h0(ph-1) ----
#pragma unroll
            for (int kt = 0; kt < 4; ++kt)
#pragma unroll
                for (int t4 = 0; t4 < 4; ++t4)
                    acc[t4] = __builtin_amdgcn_mfma_f32_16x16x32_bf16(a0[kt], wh0[t4][kt], acc[t4], 0, 0, 0);

            // ---- EW layer 0 -> h0[pp] ----
#pragma unroll
            for (int q = 0; q < 4; ++q){
                float iv = acc[0][q], fv = acc[1][q], gv = acc[2][q], ov = acc[3][q];
                float af = 1.f + __builtin_amdgcn_exp2f(-K1 * fv);
                float ai = 1.f + __builtin_amdgcn_exp2f(-K1 * iv);
                float bg = 1.f + __builtin_amdgcn_exp2f( K2 * gv);
                float cn = c0[q] * __builtin_amdgcn_rcpf(af)
                         + (bg - 2.f) * __builtin_amdgcn_rcpf(ai * bg);
                c0[q] = cn;
                float ao = 1.f + __builtin_amdgcn_exp2f(-K1 * ov);
                float bc = 1.f + __builtin_amdgcn_exp2f( K2 * cn);
                float hv = (bc - 2.f) * __builtin_amdgcn_rcpf(ao * bc);
                *(ushort_t*)(wrq[q] + WRO) = f2b(hv);
            }

            // ---- L1 (t = ph-1): acc = b1 + Wx1 @ h0(ph-1) + Wh1 @ h1(ph-2) ----
            if (ph > 0){
#pragma unroll
                for (int t4 = 0; t4 < 4; ++t4){
                    f32x4 tmp = {b1v[t4], b1v[t4], b1v[t4], b1v[t4]};
                    acc[t4] = tmp;
                }
#pragma unroll
                for (int kt = 0; kt < 4; ++kt)
#pragma unroll
                    for (int t4 = 0; t4 < 4; ++t4){
                        acc[t4] = __builtin_amdgcn_mfma_f32_16x16x32_bf16(a0[kt], wx1r[t4][kt], acc[t4], 0, 0, 0);
                        acc[t4] = __builtin_amdgcn_mfma_f32_16x16x32_bf16(ah[kt], wh1[t4][kt], acc[t4], 0, 0, 0);
                    }
#pragma unroll
                for (int q = 0; q < 4; ++q){
                    float iv = acc[0][q], fv = acc[1][q], gv = acc[2][q], ov = acc[3][q];
                    float af = 1.f + __builtin_amdgcn_exp2f(-K1 * fv);
                    float ai = 1.f + __builtin_amdgcn_exp2f(-K1 * iv);
                    float bg = 1.f + __builtin_amdgcn_exp2f( K2 * gv);
                    float cn = c1[q] * __builtin_amdgcn_rcpf(af)
                             + (bg - 2.f) * __builtin_amdgcn_rcpf(ai * bg);
                    c1[q] = cn;
                    float ao = 1.f + __builtin_amdgcn_exp2f(-K1 * ov);
                    float bc = 1.f + __builtin_amdgcn_exp2f( K2 * cn);
                    float hv = (bc - 2.f) * __builtin_amdgcn_rcpf(ao * bc);
                    *(ushort_t*)(wrq[q] + 8192 + WRO) = f2b(hv);
                    if (ph >= 57){
                        int row = g * 4 + q;
                        outB[((bcb + row) * 8 + ((ph - 1) & 7)) * 128 + wid * 16 + r0] = f2b(hv);
                    }
                }
            }

            // ---- X0 prefetch for t = ph+1 into (now dead) acc ----
            if (ph < 63){
#pragma unroll
                for (int t4 = 0; t4 < 4; ++t4)
#pragma unroll
                    for (int q = 0; q < 4; ++q)
                        acc[t4][q] = *(const float*)(xp[q] + t4 * 512);
                long d = (tnn == 7) ? -14336L : 2048L;
                tnn = (tnn == 7) ? 0 : tnn + 1;
#pragma unroll
                for (int q = 0; q < 4; ++q) xp[q] += d;
            }
            __syncthreads();
        }
    }

    // ---- epilogue phase ph = 64: L1 only (t = 63), reads buffers of ph=63 ----
    {
        bf16x8 a0[4], ah[4];
#pragma unroll
        for (int kt = 0; kt < 4; ++kt){
            a0[kt] = *(const bf16x8*)(adr[kt] + 4096);
            ah[kt] = *(const bf16x8*)(adr[kt] + 8192 + 4096);
        }
        f32x4 acc2[4];
#pragma unroll
        for (int t4 = 0; t4 < 4; ++t4){
            f32x4 tmp = {b1v[t4], b1v[t4], b1v[t4], b1v[t4]};
            acc2[t4] = tmp;
        }
#pragma unroll
        for (int kt = 0; kt < 4; ++kt)
#pragma unroll
            for (int t4 = 0; t4 < 4; ++t4){
                acc2[t4] = __builtin_amdgcn_mfma_f32_16x16x32_bf16(a0[kt], wx1r[t4][kt], acc2[t4], 0, 0, 0);
                acc2[t4] = __builtin_amdgcn_mfma_f32_16x16x32_bf16(ah[kt], wh1[t4][kt], acc2[t4], 0, 0, 0);
            }
#pragma unroll
        for (int q = 0; q < 4; ++q){
            float iv = acc2[0][q], fv = acc2[1][q], gv = acc2[2][q], ov = acc2[3][q];
            float af = 1.f + __builtin_amdgcn_exp2f(-K1 * fv);
            float ai = 1.f + __builtin_amdgcn_exp2f(-K1 * iv);
            float bg = 1.f + __builtin_amdgcn_exp2f( K2 * gv);
            float cn = c1[q] * __builtin_amdgcn_rcpf(af)
                     + (bg - 2.f) * __builtin_amdgcn_rcpf(ai * bg);
            float ao = 1.f + __builtin_amdgcn_exp2f(-K1 * ov);
            float bc = 1.f + __builtin_amdgcn_exp2f( K2 * cn);
            float hv = (bc - 2.f) * __builtin_amdgcn_rcpf(ao * bc);
            int row = g * 4 + q;
            outB[((bcb + row) * 8 + 7) * 128 + wid * 16 + r0] = f2b(hv);
        }
    }
}

// ---------- fused tail: conv1d(SAME,K=3) -> ssm -> outp(+resid xn) -> proj ----------
__global__ __launch_bounds__(256) void tail_k(
    const ushort_t* __restrict__ ls, const ushort_t* __restrict__ cWk,
    const float* __restrict__ cbias, const ushort_t* __restrict__ sW,
    const float* __restrict__ sbias, const ushort_t* __restrict__ oW,
    const float* __restrict__ obias, const float* __restrict__ xnF,
    const ushort_t* __restrict__ pW, const float* __restrict__ pbias,
    float* __restrict__ out)
{
    __shared__ ushort_t bufA[8192];
    __shared__ ushort_t bufB[8192];
    const int lane = threadIdx.x & 63, wave = threadIdx.x >> 6;
    const int r0 = lane & 15, g = lane >> 4;
    const int rowbase = blockIdx.x * 64;
    const int lr0 = wave * 16;

    // ---- conv ----
    {
        const int n = r0 & 7;
        bf16x8 a[3][4];
#pragma unroll
        for (int k = 0; k < 3; ++k){
            bool valid = (n + k >= 1) && (n + k <= 8);
            const ushort_t* ap = ls + (rowbase + lr0 + r0 + k - 1) * 128 + g * 8;
#pragma unroll
            for (int kt = 0; kt < 4; ++kt){
                bf16x8 z = {0,0,0,0,0,0,0,0};
                a[k][kt] = valid ? *(const bf16x8*)(ap + kt * 32) : z;
            }
        }
#pragma unroll
        for (int nt = 0; nt < 8; ++nt){
            const int col = nt * 16 + r0;
            float bv = cbias[col];
            f32x4 acc = {bv, bv, bv, bv};
#pragma unroll
            for (int k = 0; k < 3; ++k)
#pragma unroll
                for (int kt = 0; kt < 4; ++kt)
                    acc = __builtin_amdgcn_mfma_f32_16x16x32_bf16(
                            a[k][kt], *(const bf16x8*)(cWk + k * 16384 + col * 128 + kt * 32 + g * 8),
                            acc, 0, 0, 0);
#pragma unroll
            for (int q = 0; q < 4; ++q){
                int row = lr0 + g * 4 + q;
                bufA[row * 128 + (col ^ ((row & 7) << 3))] = f2b(acc[q]);
            }
        }
    }
    __syncthreads();
    // ---- ssm: bufA -> bufB ----
    {
        bf16x8 a[4];
#pragma unroll
        for (int kt = 0; kt < 4; ++kt)
            a[kt] = *(const bf16x8*)(&bufA[(lr0 + r0) * 128 + ((kt * 32 + g * 8) ^ ((r0 & 7) << 3))]);
#pragma unroll
        for (int nt = 0; nt < 8; ++nt){
            const int col = nt * 16 + r0;
            float bv = sbias[col];
            f32x4 acc = {bv, bv, bv, bv};
#pragma unroll
            for (int kt = 0; kt < 4; ++kt)
                acc = __builtin_amdgcn_mfma_f32_16x16x32_bf16(
                        a[kt], *(const bf16x8*)(sW + col * 128 + kt * 32 + g * 8), acc, 0, 0, 0);
#pragma unroll
            for (int q = 0; q < 4; ++q){
                int row = lr0 + g * 4 + q;
                bufB[row * 128 + (col ^ ((row & 7) << 3))] = f2b(acc[q]);
            }
        }
    }
    __syncthreads();
    // ---- outp + resid: bufB -> bufA ----
    {
        bf16x8 a[4];
#pragma unroll
        for (int kt = 0; kt < 4; ++kt)
            a[kt] = *(const bf16x8*)(&bufB[(lr0 + r0) * 128 + ((kt * 32 + g * 8) ^ ((r0 & 7) << 3))]);
#pragma unroll
        for (int nt = 0; nt < 8; ++nt){
            const int col = nt * 16 + r0;
            float bv = obias[col];
            f32x4 acc = {bv, bv, bv, bv};
#pragma unroll
            for (int kt = 0; kt < 4; ++kt)
                acc = __builtin_amdgcn_mfma_f32_16x16x32_bf16(
                        a[kt], *(const bf16x8*)(oW + col * 128 + kt * 32 + g * 8), acc, 0, 0, 0);
#pragma unroll
            for (int q = 0; q < 4; ++q){
                int row = lr0 + g * 4 + q;
                float v = acc[q] + xnF[(rowbase + row) * 128 + col];
                bufA[row * 128 + (col ^ ((row & 7) << 3))] = f2b(v);
            }
        }
    }
    __syncthreads();
    // ---- proj: bufA -> out (96 cols, f32) ----
    {
        bf16x8 a[4];
#pragma unroll
        for (int kt = 0; kt < 4; ++kt)
            a[kt] = *(const bf16x8*)(&bufA[(lr0 + r0) * 128 + ((kt * 32 + g * 8) ^ ((r0 & 7) << 3))]);
#pragma unroll
        for (int nt = 0; nt < 6; ++nt){
            const int col = nt * 16 + r0;
            float bv = pbias[col];
            f32x4 acc = {bv, bv, bv, bv};
#pragma unroll
            for (int kt = 0; kt < 4; ++kt)
                acc = __builtin_amdgcn_mfma_f32_16x16x32_bf16(
                        a[kt], *(const bf16x8*)(pW + col * 128 + kt * 32 + g * 8), acc, 0, 0, 0);
#pragma unroll
            for (int q = 0; q < 4; ++q)
                out[(rowbase + lr0 + g * 4 + q) * 96 + col] = acc[q];
        }
    }
}

// ---------- launch ----------
extern "C" void kernel_launch(void* const* d_in, const int* in_sizes, int n_in,
                              void* d_out, int out_size, void* d_ws, size_t ws_size,
                              hipStream_t stream)
{
    const float* x   = (const float*)d_in[0];
    const float* eW  = (const float*)d_in[1];
    const float* eb  = (const float*)d_in[2];
    const float* lng = (const float*)d_in[3];
    const float* lnb = (const float*)d_in[4];
    const float* vW  = (const float*)d_in[9];
    const float* vb  = (const float*)d_in[10];
    const float* Wx  = (const float*)d_in[11];
    const float* Wh  = (const float*)d_in[12];
    const float* lb  = (const float*)d_in[13];
    const float* cW  = (const float*)d_in[14];
    const float* cb_ = (const float*)d_in[15];
    const float* sW  = (const float*)d_in[16];
    const float* sb  = (const float*)d_in[17];
    const float* oW  = (const float*)d_in[18];
    const float* ob  = (const float*)d_in[19];
    const float* pW  = (const float*)d_in[20];
    const float* pb  = (const float*)d_in[21];

    char* ws = (char*)d_ws;
    float*    xnF = (float*)   (ws + 0);          // 5376x128 f32
    ushort_t* xnB = (ushort_t*)(ws + 2752512);    // 5376x128 bf16
    ushort_t* c0B = (ushort_t*)(ws + 4128768);    // ctx0 bf16
    float*    X0F = (float*)   (ws + 5505024);    // 5376x512 f32
    ushort_t* lsB = (ushort_t*)(ws + 16515072);   // lstm out bf16
    ushort_t* wb  = (ushort_t*)(ws + 22020096);   // bf16 weights

    prep_k<<<dim3(256, 9), 256, 0, stream>>>(vW, Wx, Wh, cW, sW, oW, pW, wb);
    embed_ln_k<<<672, 128, 0, stream>>>(x, eW, eb, lng, lnb, xnF, xnB);
    // ctx0 = xn @ vW^T + vb   (attention collapses to identity on v)
    mm16_k<<<84, 256, 0, stream>>>(xnB, wb + 0,      vb, nullptr, nullptr, c0B, 128);
    // X0 = ctx0 @ Wx0^T + b0
    mm16_k<<<84, 256, 0, stream>>>(c0B, wb + 16384,  lb, nullptr, X0F,     nullptr, 512);
    lstm_k<<<42, 512, 0, stream>>>(X0F, wb + 81920, wb + 147456, wb + 212992, lb, lsB);
    tail_k<<<84, 256, 0, stream>>>(lsB, wb + 278528, cb_, wb + 327680, sb,
                                   wb + 344064, ob, xnF, wb + 360448, pb, (float*)d_out);
}